// Round 1
// baseline (118.000 us; speedup 1.0000x reference)
//
#include <hip/hip_runtime.h>
#include <math.h>

#define N_PIX 2304   // H*W = 48*48
#define CDIM  256    // HDIM
#define KDIM  2048
#define TOPK  204

// ---------------- Kernel 1: per-pixel inverse L2 norm of x rows ----------------
// x layout: (1, 256, 48, 48) -> x[c*N_PIX + p]
__global__ void k_xnorm(const float* __restrict__ x, float* __restrict__ rnorm) {
    int p = blockIdx.x * 256 + threadIdx.x;   // 9 blocks * 256 = 2304 exactly
    float s = 0.f;
    #pragma unroll 8
    for (int c = 0; c < CDIM; ++c) {
        float v = x[c * N_PIX + p];
        s = fmaf(v, v, s);
    }
    rnorm[p] = 1.0f / fmaxf(sqrtf(s), 1e-12f);
}

// ---------------- Kernel 2: build normalized xn (p-major, 2304 x 256) ----------------
__global__ void k_xn_build(const float* __restrict__ x, const float* __restrict__ rnorm,
                           float* __restrict__ xn) {
    __shared__ float tile[64][65];
    int p0 = blockIdx.x * 64;   // 36 tiles
    int c0 = blockIdx.y * 64;   // 4 tiles
    int t = threadIdx.x;
    #pragma unroll
    for (int i = 0; i < 16; ++i) {
        int l = t + i * 256;
        int cl = l >> 6, pl = l & 63;
        tile[cl][pl] = x[(c0 + cl) * N_PIX + p0 + pl];   // coalesced over p
    }
    __syncthreads();
    #pragma unroll
    for (int i = 0; i < 16; ++i) {
        int l = t + i * 256;
        int pl = l >> 6, cl = l & 63;
        xn[(p0 + pl) * CDIM + c0 + cl] = tile[cl][pl] * rnorm[p0 + pl];  // coalesced over c
    }
}

// ---------------- Kernel 3: normalized feat rows (2048 x 256) ----------------
__global__ void k_fnorm(const float* __restrict__ feat, float* __restrict__ fnorm) {
    int row  = blockIdx.x * 4 + (threadIdx.x >> 6);   // 512 blocks * 4 rows
    int lane = threadIdx.x & 63;
    float4 v = *(const float4*)(feat + (size_t)row * CDIM + lane * 4);
    float s = v.x*v.x + v.y*v.y + v.z*v.z + v.w*v.w;
    #pragma unroll
    for (int off = 32; off; off >>= 1) s += __shfl_xor(s, off, 64);
    float rn = 1.0f / fmaxf(sqrtf(s), 1e-12f);
    float4 o; o.x = v.x*rn; o.y = v.y*rn; o.z = v.z*rn; o.w = v.w*rn;
    *(float4*)(fnorm + (size_t)row * CDIM + lane * 4) = o;
}

// ---------------- Kernel 4: fp32 GEMM  score = xn @ fnorm^T ----------------
// A (2304x256 row-major), B (2048x256 row-major), C (2304x2048 row-major)
// 64x64 tile, 4x4 per thread, KC=32
__global__ __launch_bounds__(256) void k_gemm(const float* __restrict__ A,
                                              const float* __restrict__ B,
                                              float* __restrict__ C) {
    __shared__ __align__(16) float As[32][68];  // [k][m], pitch 68 (16B-aligned rows, spreads banks)
    __shared__ __align__(16) float Bs[32][68];  // [k][n]
    int t  = threadIdx.x;
    int tx = t & 15, ty = t >> 4;
    int m0 = blockIdx.y * 64;
    int n0 = blockIdx.x * 64;
    float acc[4][4] = {};
    for (int k0 = 0; k0 < 256; k0 += 32) {
        #pragma unroll
        for (int i = 0; i < 2; ++i) {
            int g  = t + i * 256;          // 512 float4 groups per operand
            int r  = g >> 3;               // tile row 0..63
            int k4 = g & 7;                // which float4 in the 32-wide k chunk
            float4 va = *(const float4*)(A + (size_t)(m0 + r) * 256 + k0 + k4 * 4);
            As[k4*4+0][r] = va.x; As[k4*4+1][r] = va.y;
            As[k4*4+2][r] = va.z; As[k4*4+3][r] = va.w;
            float4 vb = *(const float4*)(B + (size_t)(n0 + r) * 256 + k0 + k4 * 4);
            Bs[k4*4+0][r] = vb.x; Bs[k4*4+1][r] = vb.y;
            Bs[k4*4+2][r] = vb.z; Bs[k4*4+3][r] = vb.w;
        }
        __syncthreads();
        #pragma unroll
        for (int kk = 0; kk < 32; ++kk) {
            float4 a = *(const float4*)&As[kk][ty * 4];
            float4 b = *(const float4*)&Bs[kk][tx * 4];
            float av[4] = {a.x, a.y, a.z, a.w};
            float bv[4] = {b.x, b.y, b.z, b.w};
            #pragma unroll
            for (int i = 0; i < 4; ++i)
                #pragma unroll
                for (int j = 0; j < 4; ++j)
                    acc[i][j] = fmaf(av[i], bv[j], acc[i][j]);
        }
        __syncthreads();
    }
    #pragma unroll
    for (int i = 0; i < 4; ++i) {
        float4 o; o.x = acc[i][0]; o.y = acc[i][1]; o.z = acc[i][2]; o.w = acc[i][3];
        *(float4*)(C + (size_t)(m0 + ty * 4 + i) * KDIM + n0 + tx * 4) = o;
    }
}

// ---------------- Kernel 5: passthrough copy x -> out[0:256] ----------------
__global__ void k_copy(const float* __restrict__ x, float* __restrict__ out) {
    int i = blockIdx.x * 256 + threadIdx.x;   // 576 blocks, float4 each
    ((float4*)out)[i] = ((const float4*)x)[i];
}

// exclusive scan over 256 threads
__device__ __forceinline__ int exclScan256(int v, int* scr) {
    int t = threadIdx.x;
    scr[t] = v;
    __syncthreads();
    #pragma unroll
    for (int off = 1; off < 256; off <<= 1) {
        int a = (t >= off) ? scr[t - off] : 0;
        __syncthreads();
        scr[t] += a;
        __syncthreads();
    }
    int incl = scr[t];
    __syncthreads();
    return incl - v;
}

// ---------------- Kernel 6: softmax + exact top-204 select + weighted gather ----------------
__global__ __launch_bounds__(256) void k_topk(const float* __restrict__ score,
                                              const float* __restrict__ feat,
                                              const float* __restrict__ label,
                                              float* __restrict__ out) {
    int p = blockIdx.x;
    int t = threadIdx.x;
    __shared__ float    fscr[8];
    __shared__ int      iscr[256];
    __shared__ unsigned hist[256];
    __shared__ int      sfx[256];
    __shared__ int      selBinS;
    __shared__ int      selIdx[TOPK];
    __shared__ float    selW[TOPK];
    __shared__ float    ypart[256];

    // load 8 contiguous scores per thread (global-index order preserved per thread)
    const float* srow = score + (size_t)p * KDIM;
    float4 v0 = *(const float4*)(srow + t * 8);
    float4 v1 = *(const float4*)(srow + t * 8 + 4);
    float s[8] = {v0.x, v0.y, v0.z, v0.w, v1.x, v1.y, v1.z, v1.w};
    unsigned u[8];
    #pragma unroll
    for (int j = 0; j < 8; ++j) {
        unsigned b = __float_as_uint(s[j]);
        u[j] = (b & 0x80000000u) ? ~b : (b | 0x80000000u);  // monotone key: float desc == uint desc
    }

    // row max
    float m = s[0];
    #pragma unroll
    for (int j = 1; j < 8; ++j) m = fmaxf(m, s[j]);
    #pragma unroll
    for (int off = 32; off; off >>= 1) m = fmaxf(m, __shfl_xor(m, off, 64));
    if ((t & 63) == 0) fscr[t >> 6] = m;
    __syncthreads();
    m = fmaxf(fmaxf(fscr[0], fscr[1]), fmaxf(fscr[2], fscr[3]));
    __syncthreads();

    // softmax denominator over full row
    float e[8]; float d = 0.f;
    #pragma unroll
    for (int j = 0; j < 8; ++j) { e[j] = expf(s[j] - m); d += e[j]; }
    #pragma unroll
    for (int off = 32; off; off >>= 1) d += __shfl_xor(d, off, 64);
    if ((t & 63) == 0) fscr[t >> 6] = d;
    __syncthreads();
    d = fscr[0] + fscr[1] + fscr[2] + fscr[3];
    float rd = 1.0f / d;
    __syncthreads();

    // radix select: exact key of the 204th largest
    unsigned prefix = 0; int remaining = TOPK;
    for (int pass = 0; pass < 4; ++pass) {
        int shift = 24 - 8 * pass;
        hist[t] = 0;
        __syncthreads();
        #pragma unroll
        for (int j = 0; j < 8; ++j) {
            bool ok = (pass == 0) ? true : ((u[j] >> (shift + 8)) == prefix);
            if (ok) atomicAdd(&hist[(u[j] >> shift) & 255u], 1u);
        }
        __syncthreads();
        int v = (int)hist[t];
        sfx[t] = v;
        __syncthreads();
        #pragma unroll
        for (int off = 1; off < 256; off <<= 1) {
            int a = (t + off < 256) ? sfx[t + off] : 0;
            __syncthreads();
            sfx[t] += a;
            __syncthreads();
        }
        if (sfx[t] >= remaining && (t == 255 || sfx[t + 1] < remaining)) selBinS = t;
        __syncthreads();
        int b = selBinS;
        int above = (b == 255) ? 0 : sfx[b + 1];
        remaining -= above;
        prefix = (prefix << 8) | (unsigned)b;
        __syncthreads();
    }
    unsigned tval = prefix;
    int neededEq = remaining;   // how many ties at tval to include, lowest index first

    // deterministic tie-break by global index (matches stable descending sort)
    int eqc = 0;
    #pragma unroll
    for (int j = 0; j < 8; ++j) eqc += (u[j] == tval);
    int eqBase = exclScan256(eqc, iscr);

    bool inc[8];
    int run = eqBase, nsel = 0;
    #pragma unroll
    for (int j = 0; j < 8; ++j) {
        bool isEq = (u[j] == tval);
        bool sel  = (u[j] > tval) || (isEq && run < neededEq);
        if (isEq) run++;
        inc[j] = sel;
        nsel += sel ? 1 : 0;
    }
    int base = exclScan256(nsel, iscr);
    int off2 = base;
    #pragma unroll
    for (int j = 0; j < 8; ++j) {
        if (inc[j]) {
            selIdx[off2] = t * 8 + j;
            selW[off2]   = e[j] * rd;   // softmax weight over full row
            off2++;
        }
    }
    __syncthreads();

    // out_x[c] = sum_k w_k * feat[idx_k][c]   (thread t owns channel t)
    float acc = 0.f;
    #pragma unroll 4
    for (int k = 0; k < TOPK; ++k) {
        acc = fmaf(selW[k], feat[(size_t)selIdx[k] * CDIM + t], acc);
    }
    out[(size_t)(CDIM + t) * N_PIX + p] = acc;

    // out_y[ch] = sum_k w_k * label[idx_k][ch]
    int ch = t & 3, e0 = t >> 2;
    float ya = 0.f;
    for (int k = e0; k < TOPK; k += 64) ya += selW[k] * label[(size_t)selIdx[k] * 4 + ch];
    ypart[t] = ya;
    __syncthreads();
    if (t < 4) {
        float sum = 0.f;
        #pragma unroll
        for (int i = 0; i < 64; ++i) sum += ypart[i * 4 + t];
        out[(size_t)(2 * CDIM + t) * N_PIX + p] = sum;
    }
}

extern "C" void kernel_launch(void* const* d_in, const int* in_sizes, int n_in,
                              void* d_out, int out_size, void* d_ws, size_t ws_size,
                              hipStream_t stream) {
    const float* x     = (const float*)d_in[0];   // (1,256,48,48)
    const float* feat  = (const float*)d_in[1];   // (2048,256)
    const float* label = (const float*)d_in[2];   // (2048,4)
    float* out   = (float*)d_out;                 // (1,516,48,48) = 1188864 floats
    float* score = out + 516 * N_PIX;             // (2304,2048)

    char* ws = (char*)d_ws;
    float* xn    = (float*)(ws);                          // 2304*256*4 = 2359296 B
    float* fnorm = (float*)(ws + 2359296);                // 2048*256*4 = 2097152 B
    float* rnorm = (float*)(ws + 2359296 + 2097152);      // 2304*4 B

    k_xnorm   <<<9,              256, 0, stream>>>(x, rnorm);
    k_xn_build<<<dim3(36, 4),    256, 0, stream>>>(x, rnorm, xn);
    k_fnorm   <<<512,            256, 0, stream>>>(feat, fnorm);
    k_gemm    <<<dim3(32, 36),   256, 0, stream>>>(xn, fnorm, score);
    k_copy    <<<576,            256, 0, stream>>>(x, out);
    k_topk    <<<2304,           256, 0, stream>>>(score, feat, label, out);
}

// Round 2
// 69.276 us; speedup vs baseline: 1.7033x; 1.7033x over previous
//
#include <hip/hip_runtime.h>
#include <math.h>

#define N_PIX 2304   // 48*48
#define CDIM  256
#define KDIM  2048
#define TOPK  204

typedef __attribute__((ext_vector_type(8))) short bf16x8;
typedef __attribute__((ext_vector_type(4))) float f32x4;

__device__ __forceinline__ unsigned short f2bf(float f) {
    unsigned u = __float_as_uint(f);
    unsigned r = u + 0x7FFFu + ((u >> 16) & 1u);
    return (unsigned short)(r >> 16);
}

__device__ __forceinline__ void gload16(const void* g, void* l) {
    __builtin_amdgcn_global_load_lds((const __attribute__((address_space(1))) void*)g,
                                     (__attribute__((address_space(3))) void*)l,
                                     16, 0, 0);
}

// ---------------- 1: per-pixel inverse L2 norm of x ----------------
__global__ __launch_bounds__(256) void k_xnorm(const float* __restrict__ x, float* __restrict__ rnorm) {
    __shared__ float part[4][64];
    int t = threadIdx.x, p0 = blockIdx.x * 64;
    int pl = t & 63, cg = t >> 6;
    float s = 0.f;
    #pragma unroll 8
    for (int i = 0; i < 64; ++i) {
        float v = x[(cg * 64 + i) * N_PIX + p0 + pl];
        s = fmaf(v, v, s);
    }
    part[cg][pl] = s;
    __syncthreads();
    if (t < 64) {
        float tt = part[0][t] + part[1][t] + part[2][t] + part[3][t];
        rnorm[p0 + t] = 1.0f / fmaxf(sqrtf(tt), 1e-12f);
    }
}

// ---------------- 2: normalized xn bf16 (p-major, 2304 x 256) ----------------
__global__ __launch_bounds__(256) void k_xn(const float* __restrict__ x, const float* __restrict__ rnorm,
                                            unsigned short* __restrict__ xn) {
    __shared__ float tile[64][65];
    int p0 = blockIdx.x * 64, c0 = blockIdx.y * 64, t = threadIdx.x;
    #pragma unroll
    for (int i = 0; i < 16; ++i) {
        int idx = t + i * 256;
        int cl = idx >> 6, pl = idx & 63;
        tile[cl][pl] = x[(c0 + cl) * N_PIX + p0 + pl];
    }
    __syncthreads();
    #pragma unroll
    for (int i = 0; i < 16; ++i) {
        int idx = t + i * 256;
        int pl = idx >> 6, cl = idx & 63;
        xn[(size_t)(p0 + pl) * CDIM + c0 + cl] = f2bf(tile[cl][pl] * rnorm[p0 + pl]);
    }
}

// ---------------- 3: normalized feat rows bf16 (2048 x 256) ----------------
__global__ __launch_bounds__(256) void k_fnorm(const float* __restrict__ feat, unsigned short* __restrict__ fn) {
    int row  = blockIdx.x * 4 + (threadIdx.x >> 6);
    int lane = threadIdx.x & 63;
    float4 v = *(const float4*)(feat + (size_t)row * CDIM + lane * 4);
    float s = v.x*v.x + v.y*v.y + v.z*v.z + v.w*v.w;
    #pragma unroll
    for (int off = 32; off; off >>= 1) s += __shfl_xor(s, off, 64);
    float rn = 1.0f / fmaxf(sqrtf(s), 1e-12f);
    ushort4 o;
    o.x = f2bf(v.x * rn); o.y = f2bf(v.y * rn); o.z = f2bf(v.z * rn); o.w = f2bf(v.w * rn);
    *(ushort4*)(fn + (size_t)row * CDIM + lane * 4) = o;
}

// ---------------- 4: F2T pack: [featT | labelT | zeros] bf16 (320 x 2048) ----------------
__global__ __launch_bounds__(256) void k_f2t(const float* __restrict__ feat, const float* __restrict__ label,
                                             unsigned short* __restrict__ F2T) {
    int t = threadIdx.x;
    int r0 = blockIdx.x * 64;
    int y  = blockIdx.y;
    if (y < 4) {
        __shared__ float tile[64][65];
        int c0 = y * 64;
        #pragma unroll
        for (int i = 0; i < 16; ++i) {
            int idx = t + i * 256;
            int rl = idx >> 6, cl = idx & 63;
            tile[rl][cl] = feat[(size_t)(r0 + rl) * CDIM + c0 + cl];
        }
        __syncthreads();
        #pragma unroll
        for (int i = 0; i < 16; ++i) {
            int idx = t + i * 256;
            int cr = idx >> 6, rc = idx & 63;
            F2T[(size_t)(c0 + cr) * KDIM + r0 + rc] = f2bf(tile[rc][cr]);
        }
    } else {
        int ch = t >> 6, rl = t & 63;
        F2T[(size_t)(256 + ch) * KDIM + r0 + rl] = f2bf(label[(size_t)(r0 + rl) * 4 + ch]);
        #pragma unroll
        for (int z = 0; z < 15; ++z) {
            int idx = t + z * 256;     // 3840 = 60 rows x 64 cols of zero pad
            int zr = idx >> 6, zc = idx & 63;
            F2T[(size_t)(260 + zr) * KDIM + r0 + zc] = 0;
        }
    }
}

// ---------------- 5: bf16 MFMA GEMM1  score = xn(2304x256) @ fnorm(2048x256)^T ----------------
__global__ __launch_bounds__(256) void k_gemm1(const unsigned short* __restrict__ A,
                                               const unsigned short* __restrict__ B,
                                               float* __restrict__ C) {
    __shared__ __align__(16) unsigned short smA[2][128 * 32];
    __shared__ __align__(16) unsigned short smB[2][128 * 32];
    int t = threadIdx.x, l = t & 63, w = t >> 6;
    int m0 = blockIdx.y * 128, n0 = blockIdx.x * 128;
    int wr = w >> 1, wc = w & 1;

    f32x4 acc[4][4] = {};

    // prologue: stage buf0 (k0 = 0)
    #pragma unroll
    for (int r = 0; r < 2; ++r) {
        int row = r * 64 + w * 16 + (l >> 2);
        int ch  = (l & 3) ^ ((row >> 1) & 3);
        gload16(A + (size_t)(m0 + row) * CDIM + ch * 8, &smA[0][(r * 64 + w * 16) * 32]);
        gload16(B + (size_t)(n0 + row) * CDIM + ch * 8, &smB[0][(r * 64 + w * 16) * 32]);
    }
    __syncthreads();

    for (int ks = 0; ks < 8; ++ks) {
        int cur = ks & 1;
        if (ks < 7) {
            int k0 = (ks + 1) * 32;
            #pragma unroll
            for (int r = 0; r < 2; ++r) {
                int row = r * 64 + w * 16 + (l >> 2);
                int ch  = (l & 3) ^ ((row >> 1) & 3);
                gload16(A + (size_t)(m0 + row) * CDIM + k0 + ch * 8, &smA[cur ^ 1][(r * 64 + w * 16) * 32]);
                gload16(B + (size_t)(n0 + row) * CDIM + k0 + ch * 8, &smB[cur ^ 1][(r * 64 + w * 16) * 32]);
            }
        }
        bf16x8 av[4], bv[4];
        #pragma unroll
        for (int mi = 0; mi < 4; ++mi) {
            int R = wr * 64 + mi * 16 + (l & 15);
            av[mi] = *(const bf16x8*)&smA[cur][R * 32 + (((l >> 4) ^ ((R >> 1) & 3)) << 3)];
        }
        #pragma unroll
        for (int ni = 0; ni < 4; ++ni) {
            int R = wc * 64 + ni * 16 + (l & 15);
            bv[ni] = *(const bf16x8*)&smB[cur][R * 32 + (((l >> 4) ^ ((R >> 1) & 3)) << 3)];
        }
        #pragma unroll
        for (int mi = 0; mi < 4; ++mi)
            #pragma unroll
            for (int ni = 0; ni < 4; ++ni)
                acc[mi][ni] = __builtin_amdgcn_mfma_f32_16x16x32_bf16(av[mi], bv[ni], acc[mi][ni], 0, 0, 0);
        __syncthreads();
    }

    #pragma unroll
    for (int mi = 0; mi < 4; ++mi)
        #pragma unroll
        for (int ni = 0; ni < 4; ++ni) {
            int rbase = m0 + wr * 64 + mi * 16 + (l >> 4) * 4;
            int cidx  = n0 + wc * 64 + ni * 16 + (l & 15);
            #pragma unroll
            for (int r = 0; r < 4; ++r)
                C[(size_t)(rbase + r) * KDIM + cidx] = acc[mi][ni][r];
        }
}

// ---------------- 6: passthrough x -> out[0:256] ----------------
__global__ __launch_bounds__(256) void k_copy(const float* __restrict__ x, float* __restrict__ out) {
    int i = blockIdx.x * 256 + threadIdx.x;
    ((float4*)out)[i] = ((const float4*)x)[i];
}

// ---------------- 7: softmax + bisection top-204 -> dense masked weight row (bf16) ----------------
__global__ __launch_bounds__(256) void k_select(const float* __restrict__ score,
                                                unsigned short* __restrict__ Wout) {
    int p = blockIdx.x, t = threadIdx.x, l = t & 63, w = t >> 6;
    __shared__ float red[4];
    __shared__ int   icnt[4];
    const float* srow = score + (size_t)p * KDIM;
    float4 v0 = ((const float4*)srow)[t * 2];
    float4 v1 = ((const float4*)srow)[t * 2 + 1];
    float s[8] = {v0.x, v0.y, v0.z, v0.w, v1.x, v1.y, v1.z, v1.w};

    // softmax denom over full row (|s|<=1: no max-shift needed)
    float e[8], d = 0.f;
    #pragma unroll
    for (int j = 0; j < 8; ++j) { e[j] = __expf(s[j]); d += e[j]; }
    #pragma unroll
    for (int off = 32; off; off >>= 1) d += __shfl_xor(d, off, 64);
    if (l == 0) red[w] = d;
    __syncthreads();
    float rd = 1.0f / (red[0] + red[1] + red[2] + red[3]);

    // bisection: find threshold lo with count(> lo) >= 204, interval -> 7e-7
    float lo = -1.5f, hi = 1.5f;
    for (int it = 0; it < 22; ++it) {
        float mid = 0.5f * (lo + hi);
        int c = 0;
        #pragma unroll
        for (int j = 0; j < 8; ++j) c += (s[j] > mid) ? 1 : 0;
        #pragma unroll
        for (int off = 32; off; off >>= 1) c += __shfl_xor(c, off, 64);
        __syncthreads();               // protect icnt reuse
        if (l == 0) icnt[w] = c;
        __syncthreads();
        int tot = icnt[0] + icnt[1] + icnt[2] + icnt[3];
        if (tot >= TOPK) lo = mid; else hi = mid;
    }

    unsigned short wr[8];
    #pragma unroll
    for (int j = 0; j < 8; ++j) wr[j] = (s[j] > lo) ? f2bf(e[j] * rd) : (unsigned short)0;
    bf16x8 pack;
    #pragma unroll
    for (int j = 0; j < 8; ++j) pack[j] = (short)wr[j];
    *(bf16x8*)(Wout + (size_t)p * KDIM + t * 8) = pack;
}

// ---------------- 8: GEMM2  outxy^T: C(2304x320) = W(2304x2048) @ F2T(320x2048)^T ----------------
// 4 waves split K (512 each), barrier-free double-buffered staging, LDS reduce epilogue.
__global__ __launch_bounds__(256) void k_gemm2(const unsigned short* __restrict__ W,
                                               const unsigned short* __restrict__ F2T,
                                               float* __restrict__ out) {
    __shared__ __align__(16) char sm[65536];
    int t = threadIdx.x, l = t & 63, w = t >> 6;
    int m0 = blockIdx.y * 64, n0 = blockIdx.x * 64;
    char* wbase = sm + w * 16384;           // per-wave: A@{0,4096}, B@{8192,12288}
    int   kb    = w * 512;

    f32x4 acc[4][4] = {};

    // prologue stage buf0, ks=0
    #pragma unroll
    for (int i = 0; i < 4; ++i) {
        int row = i * 16 + (l >> 2);
        int ch  = (l & 3) ^ ((row >> 1) & 3);
        gload16(W   + (size_t)(m0 + row) * KDIM + kb + ch * 8, wbase + i * 1024);
        gload16(F2T + (size_t)(n0 + row) * KDIM + kb + ch * 8, wbase + 8192 + i * 1024);
    }

    for (int ks = 0; ks < 16; ++ks) {
        int cur = ks & 1;
        if (ks < 15) {
            int koff = kb + (ks + 1) * 32;
            #pragma unroll
            for (int i = 0; i < 4; ++i) {
                int row = i * 16 + (l >> 2);
                int ch  = (l & 3) ^ ((row >> 1) & 3);
                gload16(W   + (size_t)(m0 + row) * KDIM + koff + ch * 8, wbase + (cur ^ 1) * 4096 + i * 1024);
                gload16(F2T + (size_t)(n0 + row) * KDIM + koff + ch * 8, wbase + 8192 + (cur ^ 1) * 4096 + i * 1024);
            }
            asm volatile("s_waitcnt vmcnt(8)" ::: "memory");
        } else {
            asm volatile("s_waitcnt vmcnt(0)" ::: "memory");
        }
        bf16x8 av[4], bv[4];
        #pragma unroll
        for (int mi = 0; mi < 4; ++mi) {
            int R = mi * 16 + (l & 15);
            av[mi] = *(const bf16x8*)(wbase + cur * 4096 + R * 64 + (((l >> 4) ^ ((R >> 1) & 3)) << 4));
        }
        #pragma unroll
        for (int ni = 0; ni < 4; ++ni) {
            int R = ni * 16 + (l & 15);
            bv[ni] = *(const bf16x8*)(wbase + 8192 + cur * 4096 + R * 64 + (((l >> 4) ^ ((R >> 1) & 3)) << 4));
        }
        #pragma unroll
        for (int mi = 0; mi < 4; ++mi)
            #pragma unroll
            for (int ni = 0; ni < 4; ++ni)
                acc[mi][ni] = __builtin_amdgcn_mfma_f32_16x16x32_bf16(av[mi], bv[ni], acc[mi][ni], 0, 0, 0);
    }

    // epilogue: reduce 4 waves' tiles, write transposed (channel-major) coalesced
    __syncthreads();
    float* tl = (float*)sm;                 // [2][64][65] f32 = 33280 B
    if (w >= 2) {
        float* dst = tl + (w - 2) * 64 * 65;
        #pragma unroll
        for (int mi = 0; mi < 4; ++mi)
            #pragma unroll
            for (int ni = 0; ni < 4; ++ni) {
                int rr = mi * 16 + (l >> 4) * 4;
                int cc = ni * 16 + (l & 15);
                #pragma unroll
                for (int r = 0; r < 4; ++r)
                    dst[(rr + r) * 65 + cc] = acc[mi][ni][r];
            }
    }
    __syncthreads();
    if (w < 2) {
        float* dst = tl + w * 64 * 65;
        #pragma unroll
        for (int mi = 0; mi < 4; ++mi)
            #pragma unroll
            for (int ni = 0; ni < 4; ++ni) {
                int rr = mi * 16 + (l >> 4) * 4;
                int cc = ni * 16 + (l & 15);
                #pragma unroll
                for (int r = 0; r < 4; ++r)
                    dst[(rr + r) * 65 + cc] += acc[mi][ni][r];
            }
    }
    __syncthreads();
    int pl = t & 63, cg = t >> 6;
    #pragma unroll
    for (int i = 0; i < 16; ++i) {
        int cc = cg * 16 + i;
        int c_out = n0 + cc;
        int orow;
        if (c_out < 256) orow = 256 + c_out;
        else if (c_out < 260) orow = 512 + (c_out - 256);
        else continue;
        out[(size_t)orow * N_PIX + m0 + pl] = tl[pl * 65 + cc] + tl[64 * 65 + pl * 65 + cc];
    }
}

extern "C" void kernel_launch(void* const* d_in, const int* in_sizes, int n_in,
                              void* d_out, int out_size, void* d_ws, size_t ws_size,
                              hipStream_t stream) {
    const float* x     = (const float*)d_in[0];   // (1,256,48,48)
    const float* feat  = (const float*)d_in[1];   // (2048,256)
    const float* label = (const float*)d_in[2];   // (2048,4)
    float* out   = (float*)d_out;                 // (1,516,48,48) then score
    float* score = out + 516 * N_PIX;             // (2304,2048)

    char* ws = (char*)d_ws;
    unsigned short* xn    = (unsigned short*)(ws);             // 2304*256*2 = 1179648
    unsigned short* fnorm = (unsigned short*)(ws + 1179648);   // 2048*256*2 = 1048576
    unsigned short* F2T   = (unsigned short*)(ws + 2228224);   // 320*2048*2 = 1310720
    float*          rnorm = (float*)(ws + 3538944);            // 2304*4     = 9216
    unsigned short* Wm    = (unsigned short*)(ws + 3548160);   // 2304*2048*2 = 9437184

    k_xnorm <<<36,            256, 0, stream>>>(x, rnorm);
    k_xn    <<<dim3(36, 4),   256, 0, stream>>>(x, rnorm, xn);
    k_fnorm <<<512,           256, 0, stream>>>(feat, fnorm);
    k_f2t   <<<dim3(32, 5),   256, 0, stream>>>(feat, label, F2T);
    k_gemm1 <<<dim3(16, 18),  256, 0, stream>>>(xn, fnorm, score);
    k_copy  <<<576,           256, 0, stream>>>(x, out);
    k_select<<<2304,          256, 0, stream>>>(score, Wm);
    k_gemm2 <<<dim3(5, 36),   256, 0, stream>>>(Wm, F2T, out);
}